// Round 16
// baseline (579.230 us; speedup 1.0000x reference)
//
#include <hip/hip_runtime.h>
#include <hip/hip_bf16.h>

typedef __hip_bfloat16 bf16;
typedef __attribute__((ext_vector_type(8))) short short8;
typedef __attribute__((ext_vector_type(4))) float f32x4;
typedef __attribute__((ext_vector_type(4))) unsigned short us4;
#define DEV __device__ __forceinline__

static constexpr int T_ = 8, NC = 512, NT = 512, D_ = 256, H_ = 8, NBF = 1419;
static constexpr int FT32 = 46;             // 46 f-tiles of 32 (padded 1472)
static constexpr float EPS_ = 1e-4f;
static constexpr float DN = 0.25f;          // D^-0.25
static constexpr float DIAG_SC = 0.03125f;  // 0.5 * DN^2

DEV float bf2f(unsigned short u) { return __uint_as_float(((unsigned)u) << 16); }
DEV float tofloat(bf16 x) { return __bfloat162float(x); }
DEV unsigned short f2bu(float x) { bf16 h = __float2bfloat16(x); return *(unsigned short*)&h; }

DEV float ldx(const void* p, long i, int isb) {
  if (isb) return bf2f(((const unsigned short*)p)[i]);
  return ((const float*)p)[i];
}
DEV void stx(void* p, long i, float v, int isb) {
  if (isb) ((bf16*)p)[i] = __float2bfloat16(v);
  else     ((float*)p)[i] = v;
}
DEV void unpack8(uint4 u, float* dst) {
  unsigned w[4] = {u.x, u.y, u.z, u.w};
#pragma unroll
  for (int i = 0; i < 4; i++) {
    dst[2 * i + 0] = __uint_as_float((w[i] & 0xffffu) << 16);
    dst[2 * i + 1] = __uint_as_float(w[i] & 0xffff0000u);
  }
}

// ------------------------------------------------------------------
// dtype probe (1 = bf16 inputs, 0 = fp32)
// ------------------------------------------------------------------
__global__ __launch_bounds__(256)
void detect_dtype(const void* __restrict__ x, int* __restrict__ flag)
{
  __shared__ int bad;
  if (threadIdx.x == 0) bad = 0;
  __syncthreads();
  int mybad = 0;
  for (int j = 0; j < 16; j++) {
    long i = 2L * (threadIdx.x + 256L * j);
    unsigned short u = ((const unsigned short*)x)[i];
    int e = (u >> 7) & 0xff, mant = u & 0x7f;
    bool b = (e == 0xff) || (e >= 141) || (e <= 93 && !(e == 0 && mant == 0));
    mybad += b ? 1 : 0;
  }
  atomicAdd(&bad, mybad);
  __syncthreads();
  if (threadIdx.x == 0) *flag = (bad > 1024) ? 0 : 1;
}

// proj -> bf16 [FT32*32][256], zero rows past NBF
__global__ __launch_bounds__(256)
void conv_proj(const void* __restrict__ proj, bf16* __restrict__ projB,
               const int* __restrict__ dtFlag)
{
  const int fl = *dtFlag;
  int f = blockIdx.x, t = threadIdx.x;
  float v = (f < NBF) ? ldx(proj, (long)f * 256 + t, fl) : 0.f;
  projB[(long)f * 256 + t] = __float2bfloat16(v);
}

// zero the atomic-target region
__global__ __launch_bounds__(256)
void init_zero(float* __restrict__ p)
{
  p[blockIdx.x * 256 + threadIdx.x] = 0.f;
}

// ------------------------------------------------------------------
// MFMA GEMM, 64x64 tile. cT=0: natural. cT=2: MFMA-tiled store (vQ).
// diagOut!=null: atomicAdd per-row DIAG_SC*sum_n(c^2).
// ------------------------------------------------------------------
__global__ __launch_bounds__(256)
void gemm_mfma(const void* __restrict__ A, int aMode,
               const void* __restrict__ B, const void* __restrict__ bias,
               void* __restrict__ C, int cMode, int epi, int bPerm, int cT,
               const int* __restrict__ dtFlag, float* __restrict__ diagOut,
               int M, int N, int K, long sA, int divA, long sB, int modB, long sBias)
{
  __shared__ bf16 As[64 * 40];
  __shared__ bf16 Ws[64 * 40];
  const int fl = *dtFlag;
  const int aB = (aMode == 2) ? fl : aMode;
  const int cB = (cMode == 2) ? fl : cMode;
  const int t = threadIdx.x;
  const int bz = blockIdx.z;
  const long aOff = (long)(bz / divA) * sA;
  const long bOff = (long)(bz % modB) * sB;
  const long biasOff = (long)(bz % modB) * sBias;
  const long cOff = (long)bz * (long)M * N;
  const int m0 = blockIdx.y * 64, n0 = blockIdx.x * 64;
  const int w = t >> 6, l = t & 63, quad = l >> 4, ln = l & 15;
  const int am = t >> 2, ak8 = (t & 3) * 8;
  const int wk = t & 31, wg = t >> 5;
  f32x4 acc[4] = {};

  for (int k0 = 0; k0 < K; k0 += 32) {
    if (aB == 1) {
      const uint4* src = (const uint4*)((const bf16*)A + aOff + (long)(m0 + am) * K + k0 + ak8);
      *(uint4*)(&As[am * 40 + ak8]) = *src;
    } else {
      const float* src = (const float*)A + aOff + (long)(m0 + am) * K + k0 + ak8;
      unsigned short tmp[8];
#pragma unroll
      for (int i = 0; i < 8; i++) tmp[i] = f2bu(src[i]);
      *(uint4*)(&As[am * 40 + ak8]) = *(const uint4*)tmp;
    }
    {
      int k = k0 + wk;
      int krow = bPerm ? (((k & 255) << 3) | (k >> 8)) : k;
      if (fl == 1) {
        uint4 u = *(const uint4*)((const bf16*)B + bOff + (long)krow * N + n0 + wg * 8);
        const unsigned short* us = (const unsigned short*)&u;
#pragma unroll
        for (int j = 0; j < 8; j++) Ws[(wg * 8 + j) * 40 + wk] = *(const bf16*)&us[j];
      } else {
        const float* src = (const float*)B + bOff + (long)krow * N + n0 + wg * 8;
#pragma unroll
        for (int j = 0; j < 8; j++) {
          unsigned short u = f2bu(src[j]);
          Ws[(wg * 8 + j) * 40 + wk] = *(const bf16*)&u;
        }
      }
    }
    __syncthreads();
    short8 a = *(const short8*)(&As[(16 * w + ln) * 40 + quad * 8]);
#pragma unroll
    for (int i = 0; i < 4; i++) {
      short8 b = *(const short8*)(&Ws[(16 * i + ln) * 40 + quad * 8]);
      acc[i] = __builtin_amdgcn_mfma_f32_16x16x32_bf16(a, b, acc[i], 0, 0, 0);
    }
    __syncthreads();
  }

  float s2[4] = {0.f, 0.f, 0.f, 0.f};
  if (cT == 2) {
    const int mm = m0 + 16 * w + quad * 4;
    const int tile = mm >> 5, off = mm & 31;
#pragma unroll
    for (int i = 0; i < 4; i++) {
      int n = n0 + 16 * i + ln;
      us4 cv;
#pragma unroll
      for (int r = 0; r < 4; r++) {
        float c = acc[i][r];
        if (epi >= 1) c += ldx(bias, biasOff + n, fl);
        if (epi == 2) c = fmaxf(c, 0.f);
        cv[r] = f2bu(c);
      }
      *(us4*)((bf16*)C + cOff + ((long)tile * N + n) * 32 + off) = cv;
    }
  } else {
#pragma unroll
    for (int i = 0; i < 4; i++) {
#pragma unroll
      for (int r = 0; r < 4; r++) {
        int m = m0 + 16 * w + quad * 4 + r;
        int n = n0 + 16 * i + ln;
        float c = acc[i][r];
        if (epi >= 1) c += ldx(bias, biasOff + n, fl);
        if (epi == 2) c = fmaxf(c, 0.f);
        s2[r] += c * c;
        stx(C, cOff + (long)m * N + n, c, cB);
      }
    }
  }
  if (diagOut) {
#pragma unroll
    for (int r = 0; r < 4; r++) {
      float s = s2[r];
      s += __shfl_xor(s, 1); s += __shfl_xor(s, 2);
      s += __shfl_xor(s, 4); s += __shfl_xor(s, 8);
      if (ln == 0)
        atomicAdd(&diagOut[(long)bz * M + m0 + 16 * w + quad * 4 + r], DIAG_SC * s);
    }
  }
}

// ------------------------------------------------------------------
// MFMA GEMM, 32x64 tile (2x grid parallelism for M=4096,N=256 shapes
// that land at 1 block/CU with the 64-tile). Non-batched, no perm/cT.
// Wave w: m-half = w&1, n-half = w>>1 (2 n-tiles each).
// ------------------------------------------------------------------
__global__ __launch_bounds__(256)
void gemm_mfma32(const void* __restrict__ A, int aMode,
                 const void* __restrict__ B, const void* __restrict__ bias,
                 void* __restrict__ C, int cMode, int epi,
                 const int* __restrict__ dtFlag, int M, int N, int K)
{
  __shared__ bf16 As[32 * 40];
  __shared__ bf16 Ws[64 * 40];
  const int fl = *dtFlag;
  const int aB = (aMode == 2) ? fl : aMode;
  const int cB = (cMode == 2) ? fl : cMode;
  const int t = threadIdx.x;
  const int m0 = blockIdx.y * 32, n0 = blockIdx.x * 64;
  const int w = t >> 6, l = t & 63, quad = l >> 4, ln = l & 15;
  const int am = t >> 3, ak4 = (t & 7) * 4;   // A: 32 rows x 4 elems/thread
  const int wk = t & 31, wg = t >> 5;
  const int mi = w & 1, nh = w >> 1;
  f32x4 acc[2] = {};

  for (int k0 = 0; k0 < K; k0 += 32) {
    if (aB == 1) {
      const uint2* src = (const uint2*)((const bf16*)A + (long)(m0 + am) * K + k0 + ak4);
      *(uint2*)(&As[am * 40 + ak4]) = *src;
    } else {
      const float* src = (const float*)A + (long)(m0 + am) * K + k0 + ak4;
      unsigned short tmp[4];
#pragma unroll
      for (int i = 0; i < 4; i++) tmp[i] = f2bu(src[i]);
      *(uint2*)(&As[am * 40 + ak4]) = *(const uint2*)tmp;
    }
    {
      int k = k0 + wk;
      if (fl == 1) {
        uint4 u = *(const uint4*)((const bf16*)B + (long)k * N + n0 + wg * 8);
        const unsigned short* us = (const unsigned short*)&u;
#pragma unroll
        for (int j = 0; j < 8; j++) Ws[(wg * 8 + j) * 40 + wk] = *(const bf16*)&us[j];
      } else {
        const float* src = (const float*)B + (long)k * N + n0 + wg * 8;
#pragma unroll
        for (int j = 0; j < 8; j++) {
          unsigned short u = f2bu(src[j]);
          Ws[(wg * 8 + j) * 40 + wk] = *(const bf16*)&u;
        }
      }
    }
    __syncthreads();
    short8 a = *(const short8*)(&As[(16 * mi + ln) * 40 + quad * 8]);
#pragma unroll
    for (int j = 0; j < 2; j++) {
      short8 b = *(const short8*)(&Ws[(16 * (2 * nh + j) + ln) * 40 + quad * 8]);
      acc[j] = __builtin_amdgcn_mfma_f32_16x16x32_bf16(a, b, acc[j], 0, 0, 0);
    }
    __syncthreads();
  }

#pragma unroll
  for (int j = 0; j < 2; j++) {
#pragma unroll
    for (int r = 0; r < 4; r++) {
      int m = m0 + 16 * mi + quad * 4 + r;
      int n = n0 + 16 * (2 * nh + j) + ln;
      float c = acc[j][r];
      if (epi >= 1) c += ldx(bias, n, fl);
      if (epi == 2) c = fmaxf(c, 0.f);
      stx(C, (long)m * N + n, c, cB);
    }
  }
}

// ------------------------------------------------------------------
// Wo GEMM, split-K x8 (unchanged).
// ------------------------------------------------------------------
__global__ __launch_bounds__(256)
void gemm_wo_splitk(const bf16* __restrict__ A, const void* __restrict__ B,
                    float* __restrict__ P, const int* __restrict__ dtFlag,
                    int M, int N, int K)
{
  __shared__ bf16 As[64 * 40];
  __shared__ bf16 Ws[64 * 40];
  const int fl = *dtFlag;
  const int t = threadIdx.x;
  const int z = blockIdx.z;
  const int m0 = blockIdx.y * 64, n0 = blockIdx.x * 64;
  const int w = t >> 6, l = t & 63, quad = l >> 4, ln = l & 15;
  const int am = t >> 2, ak8 = (t & 3) * 8;
  const int wk = t & 31, wg = t >> 5;
  f32x4 acc[4] = {};
  const int kbase = z * 256;

  for (int k0 = kbase; k0 < kbase + 256; k0 += 32) {
    {
      const uint4* src = (const uint4*)(A + (long)(m0 + am) * K + k0 + ak8);
      *(uint4*)(&As[am * 40 + ak8]) = *src;
    }
    {
      int k = k0 + wk;
      int krow = ((k & 255) << 3) | (k >> 8);
      if (fl == 1) {
        uint4 u = *(const uint4*)((const bf16*)B + (long)krow * N + n0 + wg * 8);
        const unsigned short* us = (const unsigned short*)&u;
#pragma unroll
        for (int j = 0; j < 8; j++) Ws[(wg * 8 + j) * 40 + wk] = *(const bf16*)&us[j];
      } else {
        const float* src = (const float*)B + (long)krow * N + n0 + wg * 8;
#pragma unroll
        for (int j = 0; j < 8; j++) {
          unsigned short u = f2bu(src[j]);
          Ws[(wg * 8 + j) * 40 + wk] = *(const bf16*)&u;
        }
      }
    }
    __syncthreads();
    short8 a = *(const short8*)(&As[(16 * w + ln) * 40 + quad * 8]);
#pragma unroll
    for (int i = 0; i < 4; i++) {
      short8 b = *(const short8*)(&Ws[(16 * i + ln) * 40 + quad * 8]);
      acc[i] = __builtin_amdgcn_mfma_f32_16x16x32_bf16(a, b, acc[i], 0, 0, 0);
    }
    __syncthreads();
  }

  float* Pz = P + (long)z * M * N;
#pragma unroll
  for (int i = 0; i < 4; i++) {
#pragma unroll
    for (int r = 0; r < 4; r++) {
      int m = m0 + 16 * w + quad * 4 + r;
      int n = n0 + 16 * i + ln;
      Pz[(long)m * N + n] = acc[i][r];
    }
  }
}

// rep[m][n] (bf16) = sum_z P[z][m][n] + bo[n]
__global__ __launch_bounds__(256)
void reduce_partials(const float* __restrict__ P, const void* __restrict__ bo,
                     bf16* __restrict__ rep, const int* __restrict__ dtFlag)
{
  const int fl = *dtFlag;
  long idx = (long)blockIdx.x * 256 + threadIdx.x;
  int n = idx & 255;
  float s = ldx(bo, n, fl);
#pragma unroll
  for (int z = 0; z < 8; z++) s += P[(long)z * 1048576 + idx];
  rep[idx] = __float2bfloat16(s);
}

__global__ __launch_bounds__(256)
void fixup_h1(bf16* __restrict__ h1, const void* __restrict__ label,
              const void* __restrict__ W1, const void* __restrict__ b1,
              const int* __restrict__ dtFlag)
{
  const int fl = *dtFlag;
  int idx = blockIdx.x * 256 + threadIdx.x;
  int m = idx >> 8, n = idx & 255;
  float c = tofloat(h1[idx]) + ldx(b1, n, fl);
#pragma unroll
  for (int j = 0; j < 3; j++)
    c += ldx(label, m * 3 + j, fl) * ldx(W1, (256 + j) * 256 + n, fl);
  h1[idx] = __float2bfloat16(fmaxf(c, 0.f));
}

// ------------------------------------------------------------------
// Key-side fused v3b (unchanged).
// ------------------------------------------------------------------
__global__ __launch_bounds__(256)
void key_fused_mfma(const bf16* __restrict__ k, const bf16* __restrict__ vQ,
                    const bf16* __restrict__ projB, const float* __restrict__ diagk,
                    float* __restrict__ ksumE, bf16* __restrict__ ctxQ,
                    float* __restrict__ mpart)
{
  __shared__ bf16 kS[32 * 264];
  __shared__ bf16 pS[64 * 40];
  __shared__ float dS[32];
  __shared__ float wredM[4];

  const int bz = blockIdx.x, ft = blockIdx.y, f0 = ft * 64;
  const int t = threadIdx.x;
  const int w = t >> 6, l = t & 63, quad = l >> 4, ln = l & 15;
  const int fmine = f0 + 16 * w + ln;
  const bool fv = fmine < NBF;

  short8 pf[8];
  {
    const bf16* prow = projB + (long)fmine * 256;
#pragma unroll
    for (int kc = 0; kc < 8; kc++)
      pf[kc] = *(const short8*)(prow + kc * 32 + quad * 8);
  }
  const bf16* kb = k + (long)bz * NC * 256;
  const bf16* vqb = vQ + (long)bz * 16 * 256 * 32;
  const float* db = diagk + bz * NC;

  f32x4 acc[4][4] = {};
  float ksumP = 0.f, mP = -1e30f;

  for (int n0 = 0; n0 < NC; n0 += 32) {
    const int nt = n0 >> 5;
    short8 bfr[4];
#pragma unroll
    for (int ei = 0; ei < 4; ei++) {
      int e = 64 * w + 16 * ei + ln;
      bfr[ei] = *(const short8*)(vqb + ((long)nt * 256 + e) * 32 + quad * 8);
    }
    {
      const int row = t >> 3, ch = (t & 7) * 32;
      const uint4* src = (const uint4*)(kb + (long)(n0 + row) * 256 + ch);
      uint4* dst = (uint4*)(&kS[row * 264 + ch]);
#pragma unroll
      for (int i = 0; i < 4; i++) dst[i] = src[i];
    }
    if (t < 32) dS[t] = db[n0 + t];
    __syncthreads();

    f32x4 dd[2][2] = {};
#pragma unroll
    for (int kc = 0; kc < 8; kc++) {
      const int hf = kc & 1;
#pragma unroll
      for (int mi = 0; mi < 2; mi++) {
        short8 a = *(const short8*)(&kS[(16 * mi + ln) * 264 + kc * 32 + quad * 8]);
        dd[mi][hf] = __builtin_amdgcn_mfma_f32_16x16x32_bf16(a, pf[kc], dd[mi][hf], 0, 0, 0);
      }
    }
#pragma unroll
    for (int mi = 0; mi < 2; mi++) {
      us4 ev;
#pragma unroll
      for (int r = 0; r < 4; r++) {
        float sc = DN * (dd[mi][0][r] + dd[mi][1][r]);
        float E = fv ? __expf(fminf(sc - dS[16 * mi + quad * 4 + r], 80.f)) : 0.f;
        unsigned short u = f2bu(E);
        ksumP += bf2f(u);
        if (fv) mP = fmaxf(mP, sc);
        ev[r] = u;
      }
      *(us4*)(&pS[(16 * w + ln) * 40 + 16 * mi + quad * 4]) = ev;
    }
    __syncthreads();

#pragma unroll
    for (int fh = 0; fh < 4; fh++) {
      short8 a = *(const short8*)(&pS[(16 * fh + ln) * 40 + quad * 8]);
#pragma unroll
      for (int ei = 0; ei < 4; ei++)
        acc[fh][ei] = __builtin_amdgcn_mfma_f32_16x16x32_bf16(a, bfr[ei], acc[fh][ei], 0, 0, 0);
    }
  }
  __syncthreads();

#pragma unroll
  for (int fh = 0; fh < 4; fh++) {
    const int ft32 = 2 * ft + (fh >> 1);
    const int f32b = 16 * (fh & 1) + quad * 4;
#pragma unroll
    for (int ei = 0; ei < 4; ei++) {
      int e = 64 * w + 16 * ei + ln;
      us4 cv;
#pragma unroll
      for (int r = 0; r < 4; r++) cv[r] = f2bu(acc[fh][ei][r]);
      *(us4*)(&ctxQ[((long)(bz * FT32 + ft32) * 256 + e) * 32 + f32b]) = cv;
    }
  }

  float s = ksumP;
  s += __shfl_xor(s, 16); s += __shfl_xor(s, 32);
  if (quad == 0 && fv) ksumE[(long)bz * NBF + fmine] = s;
  float m = mP;
#pragma unroll
  for (int off = 1; off < 64; off <<= 1) m = fmaxf(m, __shfl_xor(m, off));
  if (l == 0) wredM[w] = m;
  __syncthreads();
  if (t == 0)
    mpart[bz * 23 + ft] = fmaxf(fmaxf(wredM[0], wredM[1]), fmaxf(wredM[2], wredM[3]));
}

__global__ __launch_bounds__(64)
void mk_reduce(const float* __restrict__ mpart, float* __restrict__ mk)
{
  int bz = blockIdx.x, l = threadIdx.x;
  float m = (l < 23) ? mpart[bz * 23 + l] : -1e30f;
#pragma unroll
  for (int off = 32; off > 0; off >>= 1) m = fmaxf(m, __shfl_down(m, off));
  if (l == 0) mk[bz] = m;
}

// Sv: grid (bz=64, nt=16), atomicAdd partials (Sv pre-zeroed)
__global__ __launch_bounds__(256)
void sv_kernel_Q(const bf16* __restrict__ vQ, float* __restrict__ Sv)
{
  int bz = blockIdx.x, nt = blockIdx.y, e = threadIdx.x;
  const uint4* r4 = (const uint4*)(vQ + ((long)(bz * 16 + nt) * 256 + e) * 32);
  float s = 0.f;
#pragma unroll
  for (int i = 0; i < 4; i++) {
    float tmp[8];
    unpack8(r4[i], tmp);
#pragma unroll
    for (int j = 0; j < 8; j++) s += tmp[j];
  }
  atomicAdd(&Sv[bz * 256 + e], s);
}

// ctxQ finalize + fused ctxsum accumulation (ctxs pre-zeroed)
__global__ __launch_bounds__(256)
void ctx_finQ(bf16* __restrict__ ctxQ, const float* __restrict__ Sv,
              const float* __restrict__ mk, float* __restrict__ ctxs)
{
  int ft32 = blockIdx.x, bz = blockIdx.y, e = threadIdx.x;
  float emk = __expf(-mk[bz]);
  float sve = EPS_ * Sv[bz * 256 + e];
  uint4* row = (uint4*)(ctxQ + ((long)(bz * FT32 + ft32) * 256 + e) * 32);
  int fbase = 32 * ft32;
  float rsum = 0.f;
#pragma unroll
  for (int cchunk = 0; cchunk < 4; cchunk++) {
    float tmp[8];
    unpack8(row[cchunk], tmp);
    unsigned short out[8];
#pragma unroll
    for (int j = 0; j < 8; j++) {
      int f = fbase + cchunk * 8 + j;
      float val = (f < NBF) ? (emk * tmp[j] + sve) : 0.f;
      rsum += val;
      out[j] = f2bu(val);
    }
    row[cchunk] = *(const uint4*)out;
  }
  atomicAdd(&ctxs[bz * 256 + e], rsum);
}

// ksum finalize, parallel: grid (64, 6); ktot via atomicAdd (pre-zeroed)
__global__ __launch_bounds__(256)
void ksum_fin(float* __restrict__ ksumE, const float* __restrict__ mk,
              float* __restrict__ ksumtot)
{
  __shared__ float red[4];
  int bz = blockIdx.x, t = threadIdx.x;
  int f = blockIdx.y * 256 + t;
  float emk = __expf(-mk[bz]);
  float s = 0.f;
  if (f < NBF) {
    float kf = emk * ksumE[(long)bz * NBF + f] + (float)NC * EPS_;
    ksumE[(long)bz * NBF + f] = kf;
    s = kf;
  }
#pragma unroll
  for (int off = 32; off > 0; off >>= 1) s += __shfl_down(s, off);
  if ((t & 63) == 0) red[t >> 6] = s;
  __syncthreads();
  if (t == 0) atomicAdd(&ksumtot[bz], red[0] + red[1] + red[2] + red[3]);
}

// ------------------------------------------------------------------
// Query-side fused v3b (unchanged).
// ------------------------------------------------------------------
__global__ __launch_bounds__(256)
void q_fused_mfma(const bf16* __restrict__ q, const bf16* __restrict__ projB,
                  const float* __restrict__ diagq, const bf16* __restrict__ ctxQ,
                  const float* __restrict__ ksum, const float* __restrict__ ctxsum,
                  const float* __restrict__ ksumtot, bf16* __restrict__ merged)
{
  __shared__ bf16 qS[32 * 264];
  __shared__ bf16 projS[32 * 264];
  __shared__ bf16 eS[32 * 40];
  __shared__ float ksumS[32];
  __shared__ float dS[32];
  __shared__ float csS[256];
  __shared__ float sS[32][2];
  __shared__ float mS[32][2];

  const int bz = blockIdx.x, nt = blockIdx.y, t = threadIdx.x;
  const int w = t >> 6, l = t & 63, quad = l >> 4, ln = l & 15;
  const int mi = w & 1, fi = w >> 1;
  const int tq = bz / H_, hh = bz % H_;
  const bf16* cqb = ctxQ + (long)bz * FT32 * 256 * 32;

  {
    const int row = t >> 3, ch = (t & 7) * 32;
    const uint4* src = (const uint4*)(q + ((long)bz * NT + nt * 32 + row) * 256 + ch);
    uint4* dst = (uint4*)(&qS[row * 264 + ch]);
#pragma unroll
    for (int i = 0; i < 4; i++) dst[i] = src[i];
  }
  if (t < 32) dS[t] = diagq[(long)bz * NT + nt * 32 + t];
  csS[t] = ctxsum[bz * 256 + t];

  f32x4 acc[2][4] = {};
  float sPart[4] = {0.f, 0.f, 0.f, 0.f};
  float mPart[4] = {0.f, 0.f, 0.f, 0.f};
  __syncthreads();

  for (int ft = 0; ft < FT32; ft++) {
    const int f0 = ft * 32;
    short8 cfr[4];
#pragma unroll
    for (int i = 0; i < 4; i++) {
      int e = 16 * (4 * w + i) + ln;
      cfr[i] = *(const short8*)(cqb + ((long)ft * 256 + e) * 32 + quad * 8);
    }
    {
      const int row = t >> 3, ch = (t & 7) * 32;
      const uint4* src = (const uint4*)(projB + (long)(f0 + row) * 256 + ch);
      uint4* dst = (uint4*)(&projS[row * 264 + ch]);
#pragma unroll
      for (int i = 0; i < 4; i++) dst[i] = src[i];
    }
    if (t < 32) ksumS[t] = (f0 + t < NBF) ? ksum[(long)bz * NBF + f0 + t] : 0.f;
    __syncthreads();

    f32x4 dd0 = {}, dd1 = {};
#pragma unroll
    for (int kc = 0; kc < 8; kc += 2) {
      short8 a0 = *(const short8*)(&qS[(16 * mi + ln) * 264 + kc * 32 + quad * 8]);
      short8 b0 = *(const short8*)(&projS[(16 * fi + ln) * 264 + kc * 32 + quad * 8]);
      dd0 = __builtin_amdgcn_mfma_f32_16x16x32_bf16(a0, b0, dd0, 0, 0, 0);
      short8 a1 = *(const short8*)(&qS[(16 * mi + ln) * 264 + (kc + 1) * 32 + quad * 8]);
      short8 b1 = *(const short8*)(&projS[(16 * fi + ln) * 264 + (kc + 1) * 32 + quad * 8]);
      dd1 = __builtin_amdgcn_mfma_f32_16x16x32_bf16(a1, b1, dd1, 0, 0, 0);
    }
    const bool fv = (f0 + 16 * fi + ln) < NBF;
    const float kv = ksumS[16 * fi + ln];
#pragma unroll
    for (int r = 0; r < 4; r++) {
      float E = fv ? __expf(fminf(DN * (dd0[r] + dd1[r]), 80.f)) : 0.f;
      bf16 h = __float2bfloat16(E);
      float Er = tofloat(h);
      eS[(16 * mi + quad * 4 + r) * 40 + 16 * fi + ln] = h;
      sPart[r] += Er * kv;
      mPart[r] = fmaxf(mPart[r], Er);
    }
    __syncthreads();

#pragma unroll
    for (int mh = 0; mh < 2; mh++) {
      short8 a = *(const short8*)(&eS[(16 * mh + ln) * 40 + quad * 8]);
#pragma unroll
      for (int i = 0; i < 4; i++)
        acc[mh][i] = __builtin_amdgcn_mfma_f32_16x16x32_bf16(a, cfr[i], acc[mh][i], 0, 0, 0);
    }
  }
  __syncthreads();

#pragma unroll
  for (int r = 0; r < 4; r++) {
    float s = sPart[r], m = mPart[r];
#pragma unroll
    for (int off = 1; off < 16; off <<= 1) {
      s += __shfl_xor(s, off);
      m = fmaxf(m, __shfl_xor(m, off));
    }
    if (ln == 0) {
      sS[16 * mi + quad * 4 + r][fi] = s;
      mS[16 * mi + quad * 4 + r][fi] = m;
    }
  }
  __syncthreads();

  const float ktotv = ksumtot[bz];
#pragma unroll
  for (int mh = 0; mh < 2; mh++) {
#pragma unroll
    for (int r = 0; r < 4; r++) {
      int row = 16 * mh + quad * 4 + r;
      float st = sS[row][0] + sS[row][1];
      float mt = fmaxf(fmaxf(mS[row][0], mS[row][1]), 1e-30f);
      float c = __expf(-dS[row]) / mt;
      float inv = 1.f / (c * st + EPS_ * ktotv);
#pragma unroll
      for (int i = 0; i < 4; i++) {
        int e = 16 * (4 * w + i) + ln;
        float val = (c * acc[mh][i][r] + EPS_ * csS[e]) * inv;
        merged[((long)tq * NT + nt * 32 + row) * 2048 + hh * 256 + e] =
            __float2bfloat16(val);
      }
    }
  }
}

// ------------------------------------------------------------------
extern "C" void kernel_launch(void* const* d_in, const int* in_sizes, int n_in,
                              void* d_out, int out_size, void* d_ws, size_t ws_size,
                              hipStream_t stream)
{
  const void* x_ctx = d_in[0];
  const void* label = d_in[1];
  const void* x_tgt = d_in[2];
  const void* W1 = d_in[3];
  const void* b1 = d_in[4];
  const void* W2 = d_in[5];
  const void* b2 = d_in[6];
  const void* W3 = d_in[7];
  const void* b3 = d_in[8];
  const void* Wk = d_in[9];
  const void* bk = d_in[10];
  const void* Wv = d_in[11];
  const void* bv = d_in[12];
  const void* Wq = d_in[13];
  const void* bq = d_in[14];
  const void* Wo = d_in[15];
  const void* bo = d_in[16];
  const void* Wmu = d_in[17];
  const void* bmu = d_in[18];
  const void* proj = d_in[19];

  // Arena (floats), peak ~84 MB
  float* W = (float*)d_ws;
  const long F0 = 0, F1 = 4194304, F2 = 8388608;
  const long CTXQ_F = (long)64 * FT32 * 256 * 32 / 2;   // 12,058,624 floats
  const long F3 = F2 + CTXQ_F;
  bf16* kB = (bf16*)(W + F0);
  bf16* qB = (bf16*)(W + F0);
  bf16* rep = (bf16*)(W + F0);
  bf16* vQ = (bf16*)(W + F1);
  bf16* merged = (bf16*)(W + F1);
  bf16* h1 = (bf16*)(W + F2);
  bf16* h2 = (bf16*)(W + F2 + 524288);
  bf16* cf = (bf16*)(W + F2 + 1048576);
  bf16* ctxQ = (bf16*)(W + F2);
  float* woP = W + F2;                 // 8x1M fp32 partials, after ctxQ dead
  long o = F3;
  auto alloc = [&](long n) { float* p = W + o; o += n; return p; };
  // atomic-target region (contiguous, zeroed by init_zero)
  float* zbase = W + o;
  float* dgk = alloc(32768);
  float* dgq = alloc(32768);
  float* Sv = alloc(64 * 256);
  float* ctxs = alloc(64 * 256);
  float* ktot = alloc(64);
  alloc(192);                          // pad so init_zero never hits live data
  float* ksumE = alloc((long)64 * NBF);
  float* mpart = alloc(64 * 23);
  float* mk = alloc(64);
  int* dtFlag = (int*)alloc(64);
  bf16* projB = (bf16*)alloc((long)FT32 * 32 * 256 / 2);
  (void)ws_size; (void)in_sizes; (void)n_in; (void)out_size;

  const dim3 B(256);
  detect_dtype<<<1, B, 0, stream>>>(x_ctx, dtFlag);
  conv_proj<<<FT32 * 32, B, 0, stream>>>(proj, projB, dtFlag);
  init_zero<<<385, B, 0, stream>>>(zbase);   // dgk,dgq,Sv,ctxs,ktot (+pad)
  // 1. task-encoder MLP (bf16 activations) — 32-row tiles, 512 blocks each
  gemm_mfma32<<<dim3(4, 128), B, 0, stream>>>(
      x_ctx, 2, W1, nullptr, h1, 1, 0, dtFlag, 4096, 256, 256);
  fixup_h1<<<4096, B, 0, stream>>>(h1, label, W1, b1, dtFlag);
  gemm_mfma32<<<dim3(4, 128), B, 0, stream>>>(
      h1, 1, W2, b2, h2, 1, 2, dtFlag, 4096, 256, 256);
  gemm_mfma32<<<dim3(4, 128), B, 0, stream>>>(
      h2, 1, W3, b3, cf, 1, 2, dtFlag, 4096, 256, 256);
  // 2. k projection (fused diag), v projection (tiled -> vQ)
  gemm_mfma<<<dim3(4, 8, 64), B, 0, stream>>>(
      x_ctx, 2, Wk, bk, kB, 1, 1, 0, 0, dtFlag, dgk, 512, 256, 256, (long)512 * 256, H_, 65536L, H_, 256L);
  gemm_mfma<<<dim3(4, 8, 64), B, 0, stream>>>(
      cf, 1, Wv, bv, vQ, 1, 1, 0, 2, dtFlag, nullptr, 512, 256, 256, (long)512 * 256, H_, 65536L, H_, 256L);
  // 3. key side
  key_fused_mfma<<<dim3(64, 23), B, 0, stream>>>(kB, vQ, projB, dgk, ksumE, ctxQ, mpart);
  mk_reduce<<<64, 64, 0, stream>>>(mpart, mk);
  sv_kernel_Q<<<dim3(64, 16), B, 0, stream>>>(vQ, Sv);
  ctx_finQ<<<dim3(FT32, 64), B, 0, stream>>>(ctxQ, Sv, mk, ctxs);
  ksum_fin<<<dim3(64, 6), B, 0, stream>>>(ksumE, mk, ktot);
  // 4. q projection (fused diag)
  gemm_mfma<<<dim3(4, 8, 64), B, 0, stream>>>(
      x_tgt, 2, Wq, bq, qB, 1, 1, 0, 0, dtFlag, dgq, 512, 256, 256, (long)512 * 256, H_, 65536L, H_, 256L);
  // 5. query side -> merged [t][n][h][e]
  q_fused_mfma<<<dim3(64, 16), B, 0, stream>>>(qB, projB, dgq, ctxQ, ksumE, ctxs, ktot, merged);
  // 6. Wo split-K x8 -> fp32 partials, reduce, Wmu (32-row tiles)
  gemm_wo_splitk<<<dim3(4, 64, 8), B, 0, stream>>>(merged, Wo, woP, dtFlag, 4096, 256, 2048);
  reduce_partials<<<4096, B, 0, stream>>>(woP, bo, rep, dtFlag);
  gemm_mfma32<<<dim3(4, 128), B, 0, stream>>>(
      rep, 1, Wmu, bmu, d_out, 2, 1, dtFlag, 4096, 256, 256);
}

// Round 17
// 551.598 us; speedup vs baseline: 1.0501x; 1.0501x over previous
//
#include <hip/hip_runtime.h>
#include <hip/hip_bf16.h>

typedef __hip_bfloat16 bf16;
typedef __attribute__((ext_vector_type(8))) short short8;
typedef __attribute__((ext_vector_type(4))) float f32x4;
typedef __attribute__((ext_vector_type(4))) unsigned short us4;
#define DEV __device__ __forceinline__

static constexpr int T_ = 8, NC = 512, NT = 512, D_ = 256, H_ = 8, NBF = 1419;
static constexpr int FT32 = 46;             // 46 f-tiles of 32 (padded 1472)
static constexpr float EPS_ = 1e-4f;
static constexpr float DN = 0.25f;          // D^-0.25
static constexpr float DIAG_SC = 0.03125f;  // 0.5 * DN^2

DEV float bf2f(unsigned short u) { return __uint_as_float(((unsigned)u) << 16); }
DEV float tofloat(bf16 x) { return __bfloat162float(x); }
DEV unsigned short f2bu(float x) { bf16 h = __float2bfloat16(x); return *(unsigned short*)&h; }

DEV float ldx(const void* p, long i, int isb) {
  if (isb) return bf2f(((const unsigned short*)p)[i]);
  return ((const float*)p)[i];
}
DEV void stx(void* p, long i, float v, int isb) {
  if (isb) ((bf16*)p)[i] = __float2bfloat16(v);
  else     ((float*)p)[i] = v;
}
DEV void unpack8(uint4 u, float* dst) {
  unsigned w[4] = {u.x, u.y, u.z, u.w};
#pragma unroll
  for (int i = 0; i < 4; i++) {
    dst[2 * i + 0] = __uint_as_float((w[i] & 0xffffu) << 16);
    dst[2 * i + 1] = __uint_as_float(w[i] & 0xffff0000u);
  }
}

// ------------------------------------------------------------------
// dtype probe (1 = bf16 inputs, 0 = fp32)
// ------------------------------------------------------------------
__global__ __launch_bounds__(256)
void detect_dtype(const void* __restrict__ x, int* __restrict__ flag)
{
  __shared__ int bad;
  if (threadIdx.x == 0) bad = 0;
  __syncthreads();
  int mybad = 0;
  for (int j = 0; j < 16; j++) {
    long i = 2L * (threadIdx.x + 256L * j);
    unsigned short u = ((const unsigned short*)x)[i];
    int e = (u >> 7) & 0xff, mant = u & 0x7f;
    bool b = (e == 0xff) || (e >= 141) || (e <= 93 && !(e == 0 && mant == 0));
    mybad += b ? 1 : 0;
  }
  atomicAdd(&bad, mybad);
  __syncthreads();
  if (threadIdx.x == 0) *flag = (bad > 1024) ? 0 : 1;
}

// proj -> bf16 [FT32*32][256], zero rows past NBF
__global__ __launch_bounds__(256)
void conv_proj(const void* __restrict__ proj, bf16* __restrict__ projB,
               const int* __restrict__ dtFlag)
{
  const int fl = *dtFlag;
  int f = blockIdx.x, t = threadIdx.x;
  float v = (f < NBF) ? ldx(proj, (long)f * 256 + t, fl) : 0.f;
  projB[(long)f * 256 + t] = __float2bfloat16(v);
}

// zero the atomic-target region
__global__ __launch_bounds__(256)
void init_zero(float* __restrict__ p)
{
  p[blockIdx.x * 256 + threadIdx.x] = 0.f;
}

// ------------------------------------------------------------------
// MFMA GEMM, 64x64 tile. cT=0: natural. cT=2: MFMA-tiled store (vQ)
// with optional fused column-sum svOut (Sv for v-projection).
// diagOut!=null: atomicAdd per-row DIAG_SC*sum_n(c^2).
// ------------------------------------------------------------------
__global__ __launch_bounds__(256)
void gemm_mfma(const void* __restrict__ A, int aMode,
               const void* __restrict__ B, const void* __restrict__ bias,
               void* __restrict__ C, int cMode, int epi, int bPerm, int cT,
               const int* __restrict__ dtFlag, float* __restrict__ diagOut,
               float* __restrict__ svOut,
               int M, int N, int K, long sA, int divA, long sB, int modB, long sBias)
{
  __shared__ bf16 As[64 * 40];
  __shared__ bf16 Ws[64 * 40];
  const int fl = *dtFlag;
  const int aB = (aMode == 2) ? fl : aMode;
  const int cB = (cMode == 2) ? fl : cMode;
  const int t = threadIdx.x;
  const int bz = blockIdx.z;
  const long aOff = (long)(bz / divA) * sA;
  const long bOff = (long)(bz % modB) * sB;
  const long biasOff = (long)(bz % modB) * sBias;
  const long cOff = (long)bz * (long)M * N;
  const int m0 = blockIdx.y * 64, n0 = blockIdx.x * 64;
  const int w = t >> 6, l = t & 63, quad = l >> 4, ln = l & 15;
  const int am = t >> 2, ak8 = (t & 3) * 8;
  const int wk = t & 31, wg = t >> 5;
  f32x4 acc[4] = {};

  for (int k0 = 0; k0 < K; k0 += 32) {
    if (aB == 1) {
      const uint4* src = (const uint4*)((const bf16*)A + aOff + (long)(m0 + am) * K + k0 + ak8);
      *(uint4*)(&As[am * 40 + ak8]) = *src;
    } else {
      const float* src = (const float*)A + aOff + (long)(m0 + am) * K + k0 + ak8;
      unsigned short tmp[8];
#pragma unroll
      for (int i = 0; i < 8; i++) tmp[i] = f2bu(src[i]);
      *(uint4*)(&As[am * 40 + ak8]) = *(const uint4*)tmp;
    }
    {
      int k = k0 + wk;
      int krow = bPerm ? (((k & 255) << 3) | (k >> 8)) : k;
      if (fl == 1) {
        uint4 u = *(const uint4*)((const bf16*)B + bOff + (long)krow * N + n0 + wg * 8);
        const unsigned short* us = (const unsigned short*)&u;
#pragma unroll
        for (int j = 0; j < 8; j++) Ws[(wg * 8 + j) * 40 + wk] = *(const bf16*)&us[j];
      } else {
        const float* src = (const float*)B + bOff + (long)krow * N + n0 + wg * 8;
#pragma unroll
        for (int j = 0; j < 8; j++) {
          unsigned short u = f2bu(src[j]);
          Ws[(wg * 8 + j) * 40 + wk] = *(const bf16*)&u;
        }
      }
    }
    __syncthreads();
    short8 a = *(const short8*)(&As[(16 * w + ln) * 40 + quad * 8]);
#pragma unroll
    for (int i = 0; i < 4; i++) {
      short8 b = *(const short8*)(&Ws[(16 * i + ln) * 40 + quad * 8]);
      acc[i] = __builtin_amdgcn_mfma_f32_16x16x32_bf16(a, b, acc[i], 0, 0, 0);
    }
    __syncthreads();
  }

  float s2[4] = {0.f, 0.f, 0.f, 0.f};
  if (cT == 2) {
    const int mm = m0 + 16 * w + quad * 4;
    const int tile = mm >> 5, off = mm & 31;
#pragma unroll
    for (int i = 0; i < 4; i++) {
      int n = n0 + 16 * i + ln;
      us4 cv;
      float colsum = 0.f;
#pragma unroll
      for (int r = 0; r < 4; r++) {
        float c = acc[i][r];
        if (epi >= 1) c += ldx(bias, biasOff + n, fl);
        if (epi == 2) c = fmaxf(c, 0.f);
        colsum += c;
        cv[r] = f2bu(c);
      }
      *(us4*)((bf16*)C + cOff + ((long)tile * N + n) * 32 + off) = cv;
      if (svOut) {
        colsum += __shfl_xor(colsum, 16);
        colsum += __shfl_xor(colsum, 32);
        if (quad == 0) atomicAdd(&svOut[(long)bz * N + n], colsum);
      }
    }
  } else {
#pragma unroll
    for (int i = 0; i < 4; i++) {
#pragma unroll
      for (int r = 0; r < 4; r++) {
        int m = m0 + 16 * w + quad * 4 + r;
        int n = n0 + 16 * i + ln;
        float c = acc[i][r];
        if (epi >= 1) c += ldx(bias, biasOff + n, fl);
        if (epi == 2) c = fmaxf(c, 0.f);
        s2[r] += c * c;
        stx(C, cOff + (long)m * N + n, c, cB);
      }
    }
  }
  if (diagOut) {
#pragma unroll
    for (int r = 0; r < 4; r++) {
      float s = s2[r];
      s += __shfl_xor(s, 1); s += __shfl_xor(s, 2);
      s += __shfl_xor(s, 4); s += __shfl_xor(s, 8);
      if (ln == 0)
        atomicAdd(&diagOut[(long)bz * M + m0 + 16 * w + quad * 4 + r], DIAG_SC * s);
    }
  }
}

// ------------------------------------------------------------------
// MFMA GEMM, 32x64 tile (unchanged from round 16).
// ------------------------------------------------------------------
__global__ __launch_bounds__(256)
void gemm_mfma32(const void* __restrict__ A, int aMode,
                 const void* __restrict__ B, const void* __restrict__ bias,
                 void* __restrict__ C, int cMode, int epi,
                 const int* __restrict__ dtFlag, int M, int N, int K)
{
  __shared__ bf16 As[32 * 40];
  __shared__ bf16 Ws[64 * 40];
  const int fl = *dtFlag;
  const int aB = (aMode == 2) ? fl : aMode;
  const int cB = (cMode == 2) ? fl : cMode;
  const int t = threadIdx.x;
  const int m0 = blockIdx.y * 32, n0 = blockIdx.x * 64;
  const int w = t >> 6, l = t & 63, quad = l >> 4, ln = l & 15;
  const int am = t >> 3, ak4 = (t & 7) * 4;
  const int wk = t & 31, wg = t >> 5;
  const int mi = w & 1, nh = w >> 1;
  f32x4 acc[2] = {};

  for (int k0 = 0; k0 < K; k0 += 32) {
    if (aB == 1) {
      const uint2* src = (const uint2*)((const bf16*)A + (long)(m0 + am) * K + k0 + ak4);
      *(uint2*)(&As[am * 40 + ak4]) = *src;
    } else {
      const float* src = (const float*)A + (long)(m0 + am) * K + k0 + ak4;
      unsigned short tmp[4];
#pragma unroll
      for (int i = 0; i < 4; i++) tmp[i] = f2bu(src[i]);
      *(uint2*)(&As[am * 40 + ak4]) = *(const uint2*)tmp;
    }
    {
      int k = k0 + wk;
      if (fl == 1) {
        uint4 u = *(const uint4*)((const bf16*)B + (long)k * N + n0 + wg * 8);
        const unsigned short* us = (const unsigned short*)&u;
#pragma unroll
        for (int j = 0; j < 8; j++) Ws[(wg * 8 + j) * 40 + wk] = *(const bf16*)&us[j];
      } else {
        const float* src = (const float*)B + (long)k * N + n0 + wg * 8;
#pragma unroll
        for (int j = 0; j < 8; j++) {
          unsigned short u = f2bu(src[j]);
          Ws[(wg * 8 + j) * 40 + wk] = *(const bf16*)&u;
        }
      }
    }
    __syncthreads();
    short8 a = *(const short8*)(&As[(16 * mi + ln) * 40 + quad * 8]);
#pragma unroll
    for (int j = 0; j < 2; j++) {
      short8 b = *(const short8*)(&Ws[(16 * (2 * nh + j) + ln) * 40 + quad * 8]);
      acc[j] = __builtin_amdgcn_mfma_f32_16x16x32_bf16(a, b, acc[j], 0, 0, 0);
    }
    __syncthreads();
  }

#pragma unroll
  for (int j = 0; j < 2; j++) {
#pragma unroll
    for (int r = 0; r < 4; r++) {
      int m = m0 + 16 * mi + quad * 4 + r;
      int n = n0 + 16 * (2 * nh + j) + ln;
      float c = acc[j][r];
      if (epi >= 1) c += ldx(bias, n, fl);
      if (epi == 2) c = fmaxf(c, 0.f);
      stx(C, (long)m * N + n, c, cB);
    }
  }
}

// ------------------------------------------------------------------
// Wo GEMM, split-K x8 (unchanged).
// ------------------------------------------------------------------
__global__ __launch_bounds__(256)
void gemm_wo_splitk(const bf16* __restrict__ A, const void* __restrict__ B,
                    float* __restrict__ P, const int* __restrict__ dtFlag,
                    int M, int N, int K)
{
  __shared__ bf16 As[64 * 40];
  __shared__ bf16 Ws[64 * 40];
  const int fl = *dtFlag;
  const int t = threadIdx.x;
  const int z = blockIdx.z;
  const int m0 = blockIdx.y * 64, n0 = blockIdx.x * 64;
  const int w = t >> 6, l = t & 63, quad = l >> 4, ln = l & 15;
  const int am = t >> 2, ak8 = (t & 3) * 8;
  const int wk = t & 31, wg = t >> 5;
  f32x4 acc[4] = {};
  const int kbase = z * 256;

  for (int k0 = kbase; k0 < kbase + 256; k0 += 32) {
    {
      const uint4* src = (const uint4*)(A + (long)(m0 + am) * K + k0 + ak8);
      *(uint4*)(&As[am * 40 + ak8]) = *src;
    }
    {
      int k = k0 + wk;
      int krow = ((k & 255) << 3) | (k >> 8);
      if (fl == 1) {
        uint4 u = *(const uint4*)((const bf16*)B + (long)krow * N + n0 + wg * 8);
        const unsigned short* us = (const unsigned short*)&u;
#pragma unroll
        for (int j = 0; j < 8; j++) Ws[(wg * 8 + j) * 40 + wk] = *(const bf16*)&us[j];
      } else {
        const float* src = (const float*)B + (long)krow * N + n0 + wg * 8;
#pragma unroll
        for (int j = 0; j < 8; j++) {
          unsigned short u = f2bu(src[j]);
          Ws[(wg * 8 + j) * 40 + wk] = *(const bf16*)&u;
        }
      }
    }
    __syncthreads();
    short8 a = *(const short8*)(&As[(16 * w + ln) * 40 + quad * 8]);
#pragma unroll
    for (int i = 0; i < 4; i++) {
      short8 b = *(const short8*)(&Ws[(16 * i + ln) * 40 + quad * 8]);
      acc[i] = __builtin_amdgcn_mfma_f32_16x16x32_bf16(a, b, acc[i], 0, 0, 0);
    }
    __syncthreads();
  }

  float* Pz = P + (long)z * M * N;
#pragma unroll
  for (int i = 0; i < 4; i++) {
#pragma unroll
    for (int r = 0; r < 4; r++) {
      int m = m0 + 16 * w + quad * 4 + r;
      int n = n0 + 16 * i + ln;
      Pz[(long)m * N + n] = acc[i][r];
    }
  }
}

// rep[m][n] (bf16) = sum_z P[z][m][n] + bo[n]
__global__ __launch_bounds__(256)
void reduce_partials(const float* __restrict__ P, const void* __restrict__ bo,
                     bf16* __restrict__ rep, const int* __restrict__ dtFlag)
{
  const int fl = *dtFlag;
  long idx = (long)blockIdx.x * 256 + threadIdx.x;
  int n = idx & 255;
  float s = ldx(bo, n, fl);
#pragma unroll
  for (int z = 0; z < 8; z++) s += P[(long)z * 1048576 + idx];
  rep[idx] = __float2bfloat16(s);
}

__global__ __launch_bounds__(256)
void fixup_h1(bf16* __restrict__ h1, const void* __restrict__ label,
              const void* __restrict__ W1, const void* __restrict__ b1,
              const int* __restrict__ dtFlag)
{
  const int fl = *dtFlag;
  int idx = blockIdx.x * 256 + threadIdx.x;
  int m = idx >> 8, n = idx & 255;
  float c = tofloat(h1[idx]) + ldx(b1, n, fl);
#pragma unroll
  for (int j = 0; j < 3; j++)
    c += ldx(label, m * 3 + j, fl) * ldx(W1, (256 + j) * 256 + n, fl);
  h1[idx] = __float2bfloat16(fmaxf(c, 0.f));
}

// ------------------------------------------------------------------
// Key-side fused v3b (unchanged).
// ------------------------------------------------------------------
__global__ __launch_bounds__(256)
void key_fused_mfma(const bf16* __restrict__ k, const bf16* __restrict__ vQ,
                    const bf16* __restrict__ projB, const float* __restrict__ diagk,
                    float* __restrict__ ksumE, bf16* __restrict__ ctxQ,
                    float* __restrict__ mpart)
{
  __shared__ bf16 kS[32 * 264];
  __shared__ bf16 pS[64 * 40];
  __shared__ float dS[32];
  __shared__ float wredM[4];

  const int bz = blockIdx.x, ft = blockIdx.y, f0 = ft * 64;
  const int t = threadIdx.x;
  const int w = t >> 6, l = t & 63, quad = l >> 4, ln = l & 15;
  const int fmine = f0 + 16 * w + ln;
  const bool fv = fmine < NBF;

  short8 pf[8];
  {
    const bf16* prow = projB + (long)fmine * 256;
#pragma unroll
    for (int kc = 0; kc < 8; kc++)
      pf[kc] = *(const short8*)(prow + kc * 32 + quad * 8);
  }
  const bf16* kb = k + (long)bz * NC * 256;
  const bf16* vqb = vQ + (long)bz * 16 * 256 * 32;
  const float* db = diagk + bz * NC;

  f32x4 acc[4][4] = {};
  float ksumP = 0.f, mP = -1e30f;

  for (int n0 = 0; n0 < NC; n0 += 32) {
    const int nt = n0 >> 5;
    short8 bfr[4];
#pragma unroll
    for (int ei = 0; ei < 4; ei++) {
      int e = 64 * w + 16 * ei + ln;
      bfr[ei] = *(const short8*)(vqb + ((long)nt * 256 + e) * 32 + quad * 8);
    }
    {
      const int row = t >> 3, ch = (t & 7) * 32;
      const uint4* src = (const uint4*)(kb + (long)(n0 + row) * 256 + ch);
      uint4* dst = (uint4*)(&kS[row * 264 + ch]);
#pragma unroll
      for (int i = 0; i < 4; i++) dst[i] = src[i];
    }
    if (t < 32) dS[t] = db[n0 + t];
    __syncthreads();

    f32x4 dd[2][2] = {};
#pragma unroll
    for (int kc = 0; kc < 8; kc++) {
      const int hf = kc & 1;
#pragma unroll
      for (int mi = 0; mi < 2; mi++) {
        short8 a = *(const short8*)(&kS[(16 * mi + ln) * 264 + kc * 32 + quad * 8]);
        dd[mi][hf] = __builtin_amdgcn_mfma_f32_16x16x32_bf16(a, pf[kc], dd[mi][hf], 0, 0, 0);
      }
    }
#pragma unroll
    for (int mi = 0; mi < 2; mi++) {
      us4 ev;
#pragma unroll
      for (int r = 0; r < 4; r++) {
        float sc = DN * (dd[mi][0][r] + dd[mi][1][r]);
        float E = fv ? __expf(fminf(sc - dS[16 * mi + quad * 4 + r], 80.f)) : 0.f;
        unsigned short u = f2bu(E);
        ksumP += bf2f(u);
        if (fv) mP = fmaxf(mP, sc);
        ev[r] = u;
      }
      *(us4*)(&pS[(16 * w + ln) * 40 + 16 * mi + quad * 4]) = ev;
    }
    __syncthreads();

#pragma unroll
    for (int fh = 0; fh < 4; fh++) {
      short8 a = *(const short8*)(&pS[(16 * fh + ln) * 40 + quad * 8]);
#pragma unroll
      for (int ei = 0; ei < 4; ei++)
        acc[fh][ei] = __builtin_amdgcn_mfma_f32_16x16x32_bf16(a, bfr[ei], acc[fh][ei], 0, 0, 0);
    }
  }
  __syncthreads();

#pragma unroll
  for (int fh = 0; fh < 4; fh++) {
    const int ft32 = 2 * ft + (fh >> 1);
    const int f32b = 16 * (fh & 1) + quad * 4;
#pragma unroll
    for (int ei = 0; ei < 4; ei++) {
      int e = 64 * w + 16 * ei + ln;
      us4 cv;
#pragma unroll
      for (int r = 0; r < 4; r++) cv[r] = f2bu(acc[fh][ei][r]);
      *(us4*)(&ctxQ[((long)(bz * FT32 + ft32) * 256 + e) * 32 + f32b]) = cv;
    }
  }

  float s = ksumP;
  s += __shfl_xor(s, 16); s += __shfl_xor(s, 32);
  if (quad == 0 && fv) ksumE[(long)bz * NBF + fmine] = s;
  float m = mP;
#pragma unroll
  for (int off = 1; off < 64; off <<= 1) m = fmaxf(m, __shfl_xor(m, off));
  if (l == 0) wredM[w] = m;
  __syncthreads();
  if (t == 0)
    mpart[bz * 23 + ft] = fmaxf(fmaxf(wredM[0], wredM[1]), fmaxf(wredM[2], wredM[3]));
}

__global__ __launch_bounds__(64)
void mk_reduce(const float* __restrict__ mpart, float* __restrict__ mk)
{
  int bz = blockIdx.x, l = threadIdx.x;
  float m = (l < 23) ? mpart[bz * 23 + l] : -1e30f;
#pragma unroll
  for (int off = 32; off > 0; off >>= 1) m = fmaxf(m, __shfl_down(m, off));
  if (l == 0) mk[bz] = m;
}

// ctxQ finalize + fused ctxsum accumulation (ctxs pre-zeroed)
__global__ __launch_bounds__(256)
void ctx_finQ(bf16* __restrict__ ctxQ, const float* __restrict__ Sv,
              const float* __restrict__ mk, float* __restrict__ ctxs)
{
  int ft32 = blockIdx.x, bz = blockIdx.y, e = threadIdx.x;
  float emk = __expf(-mk[bz]);
  float sve = EPS_ * Sv[bz * 256 + e];
  uint4* row = (uint4*)(ctxQ + ((long)(bz * FT32 + ft32) * 256 + e) * 32);
  int fbase = 32 * ft32;
  float rsum = 0.f;
#pragma unroll
  for (int cchunk = 0; cchunk < 4; cchunk++) {
    float tmp[8];
    unpack8(row[cchunk], tmp);
    unsigned short out[8];
#pragma unroll
    for (int j = 0; j < 8; j++) {
      int f = fbase + cchunk * 8 + j;
      float val = (f < NBF) ? (emk * tmp[j] + sve) : 0.f;
      rsum += val;
      out[j] = f2bu(val);
    }
    row[cchunk] = *(const uint4*)out;
  }
  atomicAdd(&ctxs[bz * 256 + e], rsum);
}

// ksum finalize, parallel: grid (64, 6); ktot via atomicAdd (pre-zeroed)
__global__ __launch_bounds__(256)
void ksum_fin(float* __restrict__ ksumE, const float* __restrict__ mk,
              float* __restrict__ ksumtot)
{
  __shared__ float red[4];
  int bz = blockIdx.x, t = threadIdx.x;
  int f = blockIdx.y * 256 + t;
  float emk = __expf(-mk[bz]);
  float s = 0.f;
  if (f < NBF) {
    float kf = emk * ksumE[(long)bz * NBF + f] + (float)NC * EPS_;
    ksumE[(long)bz * NBF + f] = kf;
    s = kf;
  }
#pragma unroll
  for (int off = 32; off > 0; off >>= 1) s += __shfl_down(s, off);
  if ((t & 63) == 0) red[t >> 6] = s;
  __syncthreads();
  if (t == 0) atomicAdd(&ksumtot[bz], red[0] + red[1] + red[2] + red[3]);
}

// ------------------------------------------------------------------
// Query-side fused v4: 64 q-rows per block (grid 64 x 8), 2 barriers/iter,
// 32 MFMA/wave per iteration (2x round-16). Row stats wave-private.
// LDS ~57.7 KB -> 2 blocks/CU. merged [t][n][h][e].
// ------------------------------------------------------------------
__global__ __launch_bounds__(256)
void q_fused_mfma(const bf16* __restrict__ q, const bf16* __restrict__ projB,
                  const float* __restrict__ diagq, const bf16* __restrict__ ctxQ,
                  const float* __restrict__ ksum, const float* __restrict__ ctxsum,
                  const float* __restrict__ ksumtot, bf16* __restrict__ merged)
{
  __shared__ bf16 qS[64 * 264];
  __shared__ bf16 projS[32 * 264];
  __shared__ bf16 eS[64 * 40];
  __shared__ float ksumS[32];
  __shared__ float dS[64];
  __shared__ float csS[256];
  __shared__ float sS[64];
  __shared__ float mS[64];

  const int bz = blockIdx.x, nt = blockIdx.y, t = threadIdx.x;
  const int w = t >> 6, l = t & 63, quad = l >> 4, ln = l & 15;
  const int tq = bz / H_, hh = bz % H_;
  const bf16* cqb = ctxQ + (long)bz * FT32 * 256 * 32;

  // stage q tile [64][256]
  {
    const int row = t >> 2, ch = (t & 3) * 64;
    const uint4* src = (const uint4*)(q + ((long)bz * NT + nt * 64 + row) * 256 + ch);
    uint4* dst = (uint4*)(&qS[row * 264 + ch]);
#pragma unroll
    for (int i = 0; i < 4; i++) dst[i] = src[i];
    const uint4* src2 = src + 4;
    uint4* dst2 = (uint4*)(&qS[row * 264 + ch + 32]);
#pragma unroll
    for (int i = 0; i < 4; i++) dst2[i] = src2[i];
  }
  if (t < 64) dS[t] = diagq[(long)bz * NT + nt * 64 + t];
  csS[t] = ctxsum[bz * 256 + t];

  f32x4 acc[4][4] = {};           // [mh][ei]: rows 16mh+quad*4+r, e=16(4w+ei)+ln
  float sPart[4] = {0.f, 0.f, 0.f, 0.f};   // rows 16w+quad*4+r (wave-private)
  float mPart[4] = {0.f, 0.f, 0.f, 0.f};
  __syncthreads();

  for (int ft = 0; ft < FT32; ft++) {
    const int f0 = ft * 32;
    // coalesced ctxQ B-fragments (reused across 4 m-halves)
    short8 cfr[4];
#pragma unroll
    for (int i = 0; i < 4; i++) {
      int e = 16 * (4 * w + i) + ln;
      cfr[i] = *(const short8*)(cqb + ((long)ft * 256 + e) * 32 + quad * 8);
    }
    // coalesced projS staging [32 f][256 d]
    {
      const int row = t >> 3, ch = (t & 7) * 32;
      const uint4* src = (const uint4*)(projB + (long)(f0 + row) * 256 + ch);
      uint4* dst = (uint4*)(&projS[row * 264 + ch]);
#pragma unroll
      for (int i = 0; i < 4; i++) dst[i] = src[i];
    }
    if (t < 32) ksumS[t] = (f0 + t < NBF) ? ksum[(long)bz * NBF + f0 + t] : 0.f;
    __syncthreads();

    // Phase A: wave w owns rows 16w..16w+15, both f-halves (2 indep chains)
    f32x4 dd0 = {}, dd1 = {};
#pragma unroll
    for (int kc = 0; kc < 8; kc++) {
      short8 a = *(const short8*)(&qS[(16 * w + ln) * 264 + kc * 32 + quad * 8]);
      short8 b0 = *(const short8*)(&projS[(ln) * 264 + kc * 32 + quad * 8]);
      dd0 = __builtin_amdgcn_mfma_f32_16x16x32_bf16(a, b0, dd0, 0, 0, 0);
      short8 b1 = *(const short8*)(&projS[(16 + ln) * 264 + kc * 32 + quad * 8]);
      dd1 = __builtin_amdgcn_mfma_f32_16x16x32_bf16(a, b1, dd1, 0, 0, 0);
    }
    const bool fv0 = (f0 + ln) < NBF;
    const bool fv1 = (f0 + 16 + ln) < NBF;
    const float kv0 = ksumS[ln], kv1 = ksumS[16 + ln];
#pragma unroll
    for (int r = 0; r < 4; r++) {
      float E0 = fv0 ? __expf(fminf(DN * dd0[r], 80.f)) : 0.f;
      float E1 = fv1 ? __expf(fminf(DN * dd1[r], 80.f)) : 0.f;
      bf16 h0 = __float2bfloat16(E0), h1v = __float2bfloat16(E1);
      float e0 = tofloat(h0), e1 = tofloat(h1v);
      eS[(16 * w + quad * 4 + r) * 40 + ln] = h0;
      eS[(16 * w + quad * 4 + r) * 40 + 16 + ln] = h1v;
      sPart[r] += e0 * kv0 + e1 * kv1;
      mPart[r] = fmaxf(mPart[r], fmaxf(e0, e1));
    }
    __syncthreads();

    // Phase B: all 4 m-halves, 4 e-tiles each (cfr reused)
#pragma unroll
    for (int mh = 0; mh < 4; mh++) {
      short8 a = *(const short8*)(&eS[(16 * mh + ln) * 40 + quad * 8]);
#pragma unroll
      for (int i = 0; i < 4; i++)
        acc[mh][i] = __builtin_amdgcn_mfma_f32_16x16x32_bf16(a, cfr[i], acc[mh][i], 0, 0, 0);
    }
    // no trailing barrier (round-13 proof: next eS write is behind the
    // next staging barrier; staging touches projS/ksumS only)
  }
  __syncthreads();

  // wave-private row stats: reduce over 16 lanes
#pragma unroll
  for (int r = 0; r < 4; r++) {
    float s = sPart[r], m = mPart[r];
#pragma unroll
    for (int off = 1; off < 16; off <<= 1) {
      s += __shfl_xor(s, off);
      m = fmaxf(m, __shfl_xor(m, off));
    }
    if (ln == 0) {
      sS[16 * w + quad * 4 + r] = s;
      mS[16 * w + quad * 4 + r] = m;
    }
  }
  __syncthreads();

  const float ktotv = ksumtot[bz];
#pragma unroll
  for (int mh = 0; mh < 4; mh++) {
#pragma unroll
    for (int r = 0; r < 4; r++) {
      int row = 16 * mh + quad * 4 + r;
      float st = sS[row];
      float mt = fmaxf(mS[row], 1e-30f);
      float c = __expf(-dS[row]) / mt;
      float inv = 1.f / (c * st + EPS_ * ktotv);
#pragma unroll
      for (int i = 0; i < 4; i++) {
        int e = 16 * (4 * w + i) + ln;
        float val = (c * acc[mh][i][r] + EPS_ * csS[e]) * inv;
        merged[((long)tq * NT + nt * 64 + row) * 2048 + hh * 256 + e] =
            __float2bfloat16(val);
      }
    }
  }
}

// ------------------------------------------------------------------
extern "C" void kernel_launch(void* const* d_in, const int* in_sizes, int n_in,
                              void* d_out, int out_size, void* d_ws, size_t ws_size,
                              hipStream_t stream)
{
  const void* x_ctx = d_in[0];
  const void* label = d_in[1];
  const void* x_tgt = d_in[2];
  const void* W1 = d_in[3];
  const void* b1 = d_in[4];
  const void* W2 = d_in[5];
  const void* b2 = d_in[6];
  const void* W3 = d_in[7];
  const void* b3 = d_in[8];
  const void* Wk = d_in[9];
  const void* bk = d_in[10];
  const void* Wv = d_in[11];
  const void* bv = d_in[12];
  const void* Wq = d_in[13];
  const void* bq = d_in[14];
  const void* Wo = d_in[15];
  const void* bo = d_in[16];
  const void* Wmu = d_in[17];
  const void* bmu = d_in[18];
  const void* proj = d_in[19];

  // Arena (floats), peak ~84 MB
  float* W = (float*)d_ws;
  const long F0 = 0, F1 = 4194304, F2 = 8388608;
  const long CTXQ_F = (long)64 * FT32 * 256 * 32 / 2;
  const long F3 = F2 + CTXQ_F;
  bf16* kB = (bf16*)(W + F0);
  bf16* qB = (bf16*)(W + F0);
  bf16* rep = (bf16*)(W + F0);
  bf16* vQ = (bf16*)(W + F1);
  bf16* merged = (bf16*)(W + F1);
  bf16* h1 = (bf16*)(W + F2);
  bf16* h2 = (bf16*)(W + F2 + 524288);
  bf16* cf = (bf16*)(W + F2 + 1048576);
  bf16* ctxQ = (bf16*)(W + F2);
  float* woP = W + F2;
  long o = F3;
  auto alloc = [&](long n) { float* p = W + o; o += n; return p; };
  float* zbase = W + o;
  float* dgk = alloc(32768);
  float* dgq = alloc(32768);
  float* Sv = alloc(64 * 256);
  float* ctxs = alloc(64 * 256);
  float* ktot = alloc(64);
  alloc(192);
  float* ksumE = alloc((long)64 * NBF);
  float* mpart = alloc(64 * 23);
  float* mk = alloc(64);
  int* dtFlag = (int*)alloc(64);
  bf16* projB = (bf16*)alloc((long)FT32 * 32 * 256 / 2);
  (void)ws_size; (void)in_sizes; (void)n_in; (void)out_size;

  const dim3 B(256);
  detect_dtype<<<1, B, 0, stream>>>(x_ctx, dtFlag);
  conv_proj<<<FT32 * 32, B, 0, stream>>>(proj, projB, dtFlag);
  init_zero<<<385, B, 0, stream>>>(zbase);
  // 1. task-encoder MLP
  gemm_mfma32<<<dim3(4, 128), B, 0, stream>>>(
      x_ctx, 2, W1, nullptr, h1, 1, 0, dtFlag, 4096, 256, 256);
  fixup_h1<<<4096, B, 0, stream>>>(h1, label, W1, b1, dtFlag);
  gemm_mfma32<<<dim3(4, 128), B, 0, stream>>>(
      h1, 1, W2, b2, h2, 1, 2, dtFlag, 4096, 256, 256);
  gemm_mfma32<<<dim3(4, 128), B, 0, stream>>>(
      h2, 1, W3, b3, cf, 1, 2, dtFlag, 4096, 256, 256);
  // 2. k projection (fused diag), v projection (tiled -> vQ, fused Sv)
  gemm_mfma<<<dim3(4, 8, 64), B, 0, stream>>>(
      x_ctx, 2, Wk, bk, kB, 1, 1, 0, 0, dtFlag, dgk, nullptr, 512, 256, 256, (long)512 * 256, H_, 65536L, H_, 256L);
  gemm_mfma<<<dim3(4, 8, 64), B, 0, stream>>>(
      cf, 1, Wv, bv, vQ, 1, 1, 0, 2, dtFlag, nullptr, Sv, 512, 256, 256, (long)512 * 256, H_, 65536L, H_, 256L);
  // 3. key side
  key_fused_mfma<<<dim3(64, 23), B, 0, stream>>>(kB, vQ, projB, dgk, ksumE, ctxQ, mpart);
  mk_reduce<<<64, 64, 0, stream>>>(mpart, mk);
  ctx_finQ<<<dim3(FT32, 64), B, 0, stream>>>(ctxQ, Sv, mk, ctxs);
  ksum_fin<<<dim3(64, 6), B, 0, stream>>>(ksumE, mk, ktot);
  // 4. q projection (fused diag)
  gemm_mfma<<<dim3(4, 8, 64), B, 0, stream>>>(
      x_tgt, 2, Wq, bq, qB, 1, 1, 0, 0, dtFlag, dgq, nullptr, 512, 256, 256, (long)512 * 256, H_, 65536L, H_, 256L);
  // 5. query side (64-row blocks) -> merged [t][n][h][e]
  q_fused_mfma<<<dim3(64, 8), B, 0, stream>>>(qB, projB, dgq, ctxQ, ksumE, ctxs, ktot, merged);
  // 6. Wo split-K x8 -> fp32 partials, reduce, Wmu
  gemm_wo_splitk<<<dim3(4, 64, 8), B, 0, stream>>>(merged, Wo, woP, dtFlag, 4096, 256, 2048);
  reduce_partials<<<4096, B, 0, stream>>>(woP, bo, rep, dtFlag);
  gemm_mfma32<<<dim3(4, 128), B, 0, stream>>>(
      rep, 1, Wmu, bmu, d_out, 2, 1, dtFlag, 4096, 256, 256);
}